// Round 15
// baseline (301.426 us; speedup 1.0000x reference)
//
#include <hip/hip_runtime.h>
#include <math.h>

#define NN 10000
#define EE 160000
#define FI 32
#define DE 8
#define HD 64
#define TT 3
#define OD 12

// ---------------- bulk zero (cnt, cursor only) ----------------

__global__ __launch_bounds__(256) void zero_k(float4* __restrict__ base, int n4) {
  for (int i = blockIdx.x * 256 + threadIdx.x; i < n4; i += gridDim.x * 256)
    base[i] = float4{0.f, 0.f, 0.f, 0.f};
}

// ---------------- CSR construction (padded: +1 self-loop slot per row) ----------------

__global__ __launch_bounds__(256) void hist_k(const int* __restrict__ ei, int* __restrict__ cnt) {
  int e = blockIdx.x * 256 + threadIdx.x;
  if (e < EE) atomicAdd(&cnt[ei[EE + e]], 1);
}

// one-pass scan: rowptr2[i] = exclusive_scan(cnt)[i] + i  (+1 slot per row for the self loop)
__global__ __launch_bounds__(1024) void scan_k(const int* __restrict__ cnt, int* __restrict__ rowptr2) {
  __shared__ int wsum[16];
  const int tid = threadIdx.x, lane = tid & 63, wid = tid >> 6;
  const int i0 = tid * 10;
  int v[10];
  int tot = 0;
#pragma unroll
  for (int j = 0; j < 10; ++j) {
    int i = i0 + j;
    v[j] = (i < NN) ? cnt[i] : 0;
    tot += v[j];
  }
  int s = tot;
#pragma unroll
  for (int o = 1; o < 64; o <<= 1) {
    int t = __shfl_up(s, o, 64);
    if (lane >= o) s += t;
  }
  if (lane == 63) wsum[wid] = s;
  __syncthreads();
  if (wid == 0) {
    int ws = (lane < 16) ? wsum[lane] : 0;
#pragma unroll
    for (int o = 1; o < 16; o <<= 1) {
      int t = __shfl_up(ws, o, 64);
      if (lane >= o) ws += t;
    }
    if (lane < 16) wsum[lane] = ws;
  }
  __syncthreads();
  int base = s - tot + (wid > 0 ? wsum[wid - 1] : 0);
  int run = 0;
#pragma unroll
  for (int j = 0; j < 10; ++j) {
    int i = i0 + j;
    if (i < NN) rowptr2[i] = base + run + i;
    run += v[j];
  }
  if (tid == 1023) rowptr2[NN] = base + run + NN;
}

// scatter edges into CSR order; write ea_g in place (plain stores, no fp atomics)
__global__ __launch_bounds__(256) void scatter_k(const int* __restrict__ ei, const int* __restrict__ rowptr2,
                                                 int* __restrict__ cursor, int* __restrict__ src_g,
                                                 const float* __restrict__ ea, float* __restrict__ ea_g) {
  int e = blockIdx.x * 256 + threadIdx.x;
  if (e >= EE) return;
  int s = ei[e], d = ei[EE + e];
  int pos = rowptr2[d] + atomicAdd(&cursor[d], 1);
  src_g[pos] = s;
  const float4* s4 = reinterpret_cast<const float4*>(ea + (size_t)e * DE);
  float4* d4 = reinterpret_cast<float4*>(ea_g + (size_t)pos * DE);
  d4[0] = s4[0];
  d4[1] = s4[1];
}

// self-loop slot: mean of the row's edge attrs. One wave per node.
__global__ __launch_bounds__(256) void selfmean_k(const int* __restrict__ rowptr2, int* __restrict__ src_g,
                                                  float* __restrict__ ea_g) {
  int n = blockIdx.x * 4 + (threadIdx.x >> 6);
  int lane = threadIdx.x & 63;
  if (n >= NN) return;
  int r0 = rowptr2[n], r1 = rowptr2[n + 1];
  int deg = r1 - r0 - 1;
  int j = lane >> 3, dd = lane & 7;
  float s = 0.f;
  for (int base = 0; base < deg; base += 8) {
    int idx = base + j;
    if (idx < deg) s += ea_g[(size_t)(r0 + idx) * DE + dd];
  }
#pragma unroll
  for (int o = 8; o < 64; o <<= 1) s += __shfl_xor(s, o, 64);
  if (lane < 8) ea_g[(size_t)(r1 - 1) * DE + lane] = s / (float)(deg > 0 ? deg : 1);
  if (lane == 0) src_g[r1 - 1] = n;
}

// ---------------- GEMV helper: one wave = one gate; 16 nodes from LDS rows ----------------
// K = 32 (x-branch) or 64 (h-branch); inp rows are [16][K] in LDS, b128 broadcast reads.

template <int K>
__device__ __forceinline__ void gemv16(const float (&inp)[16][K],
                                       const float* __restrict__ Wl, const float* __restrict__ Wr,
                                       const float blv, const float brv, const int lane,
                                       const int conv, const int n0,
                                       float* __restrict__ xl, float* __restrict__ xr) {
  float al[16], ar[16];
#pragma unroll
  for (int j = 0; j < 16; ++j) { al[j] = blv; ar[j] = brv; }
  for (int kk = 0; kk < K; kk += 4) {
    float wl[4], wr[4];
#pragma unroll
    for (int q = 0; q < 4; ++q) {
      wl[q] = Wl[(kk + q) * HD + lane];
      wr[q] = Wr[(kk + q) * HD + lane];
    }
#pragma unroll
    for (int j = 0; j < 16; ++j) {
      const float4 v4 = *reinterpret_cast<const float4*>(&inp[j][kk]);  // LDS b128 broadcast
      al[j] = fmaf(v4.x, wl[0], al[j]); ar[j] = fmaf(v4.x, wr[0], ar[j]);
      al[j] = fmaf(v4.y, wl[1], al[j]); ar[j] = fmaf(v4.y, wr[1], ar[j]);
      al[j] = fmaf(v4.z, wl[2], al[j]); ar[j] = fmaf(v4.z, wr[2], ar[j]);
      al[j] = fmaf(v4.w, wl[3], al[j]); ar[j] = fmaf(v4.w, wr[3], ar[j]);
    }
  }
#pragma unroll
  for (int j = 0; j < 16; ++j) {
    size_t o = ((size_t)conv * NN + (n0 + j)) * HD + lane;
    xl[o] = al[j];
    xr[o] = ar[j];
  }
}

// ---------------- t=0 node phase: x-branch only (h==0 => h-branch constant) ----------------

__global__ __launch_bounds__(256, 4) void node0_k(const float* __restrict__ x_t,
                                                  const float* __restrict__ Wl_x, const float* __restrict__ bl_x,
                                                  const float* __restrict__ Wr_x, const float* __restrict__ br_x,
                                                  float* __restrict__ xl, float* __restrict__ xr) {
  const int n0 = blockIdx.x * 16;
  const int k = threadIdx.x >> 6;
  const int lane = threadIdx.x & 63;
  __shared__ float xs[16][FI];
  for (int idx = threadIdx.x; idx < 16 * FI; idx += 256)
    xs[idx >> 5][idx & 31] = x_t[(size_t)n0 * FI + idx];
  __syncthreads();
  gemv16<FI>(xs, Wl_x + (size_t)k * FI * HD, Wr_x + (size_t)k * FI * HD,
             bl_x[k * HD + lane], br_x[k * HD + lane], lane, k, n0, xl, xr);
}

// ---------------- edge phase: one wave per (conv, node); r7 inner loop (validated floor) ----------------

template <int CTRL>
__device__ __forceinline__ float dpp_ror_add(float t) {
  int r = __builtin_amdgcn_update_dpp(0, __float_as_int(t), CTRL, 0xF, 0xF, true);
  return t + __int_as_float(r);
}
#define REDUCE32(t) do { \
  t = dpp_ror_add<0x128>(t); /* row_ror:8 */ \
  t = dpp_ror_add<0x124>(t); /* row_ror:4 */ \
  t = dpp_ror_add<0x122>(t); /* row_ror:2 */ \
  t = dpp_ror_add<0x121>(t); /* row_ror:1 */ \
  t += __int_as_float(__builtin_amdgcn_ds_swizzle(__float_as_int(t), 0x401F)); /* xor16 */ \
} while (0)

__global__ __launch_bounds__(256, 4) void edge_k(
    const int* __restrict__ rowptr2, const int* __restrict__ src_g, const float* __restrict__ ea_g,
    const float* __restrict__ xl, const float* __restrict__ xr,
    const float* __restrict__ att_x, const float* __restrict__ att_h,
    const float* __restrict__ We_x, const float* __restrict__ We_h,
    float* __restrict__ acc_b, float* __restrict__ den_b) {
  const int lane = threadIdx.x & 63;
  const int wid = threadIdx.x >> 6;
  // bijective XCD swizzle for arbitrary grid size (m204 form)
  const int nwg = gridDim.x;
  const int bid = blockIdx.x;
  const int q = nwg >> 3, r = nwg & 7;
  const int xcd = bid & 7;
  const int swz = (xcd < r ? xcd * (q + 1) : r * (q + 1) + (xcd - r) * q) + (bid >> 3);
  const int w = __builtin_amdgcn_readfirstlane(swz * 4 + wid);
  const int bk = w / NN;          // conv index (scalar); 0..3 at t=0, 0..7 otherwise
  const int d = w - bk * NN;      // dst node (scalar)
  const int k = bk & 3;
  const bool isx = (bk < 4);

  const float xrv = xr[((size_t)bk * NN + d) * HD + lane];
  const float attv = (isx ? att_x : att_h)[k * HD + lane];
  const float* Wep = (isx ? We_x : We_h) + (size_t)k * DE * HD;
  float we[DE];
#pragma unroll
  for (int dd = 0; dd < DE; ++dd) we[dd] = Wep[dd * HD + lane];
  const float* xlb = xl + (size_t)bk * NN * HD;
  const float4* eg4 = reinterpret_cast<const float4*>(ea_g);

  const int r0 = rowptr2[d];
  const int r1 = rowptr2[d + 1];
  float acc = 0.f, den = 0.f;

  int p = r0;
  for (; p + 4 <= r1; p += 4) {
    const int s0 = src_g[p + 0], s1 = src_g[p + 1], s2 = src_g[p + 2], s3 = src_g[p + 3];
    const float x0 = xlb[(size_t)s0 * HD + lane];
    const float x1 = xlb[(size_t)s1 * HD + lane];
    const float x2 = xlb[(size_t)s2 * HD + lane];
    const float x3 = xlb[(size_t)s3 * HD + lane];
    const float4 a0 = eg4[2 * (p + 0)], b0 = eg4[2 * (p + 0) + 1];
    const float4 a1 = eg4[2 * (p + 1)], b1 = eg4[2 * (p + 1) + 1];
    const float4 a2 = eg4[2 * (p + 2)], b2 = eg4[2 * (p + 2) + 1];
    const float4 a3 = eg4[2 * (p + 3)], b3 = eg4[2 * (p + 3) + 1];
    float t0 = x0 + xrv, t1 = x1 + xrv, t2 = x2 + xrv, t3 = x3 + xrv;
    t0 = fmaf(a0.x, we[0], t0); t1 = fmaf(a1.x, we[0], t1); t2 = fmaf(a2.x, we[0], t2); t3 = fmaf(a3.x, we[0], t3);
    t0 = fmaf(a0.y, we[1], t0); t1 = fmaf(a1.y, we[1], t1); t2 = fmaf(a2.y, we[1], t2); t3 = fmaf(a3.y, we[1], t3);
    t0 = fmaf(a0.z, we[2], t0); t1 = fmaf(a1.z, we[2], t1); t2 = fmaf(a2.z, we[2], t2); t3 = fmaf(a3.z, we[2], t3);
    t0 = fmaf(a0.w, we[3], t0); t1 = fmaf(a1.w, we[3], t1); t2 = fmaf(a2.w, we[3], t2); t3 = fmaf(a3.w, we[3], t3);
    t0 = fmaf(b0.x, we[4], t0); t1 = fmaf(b1.x, we[4], t1); t2 = fmaf(b2.x, we[4], t2); t3 = fmaf(b3.x, we[4], t3);
    t0 = fmaf(b0.y, we[5], t0); t1 = fmaf(b1.y, we[5], t1); t2 = fmaf(b2.y, we[5], t2); t3 = fmaf(b3.y, we[5], t3);
    t0 = fmaf(b0.z, we[6], t0); t1 = fmaf(b1.z, we[6], t1); t2 = fmaf(b2.z, we[6], t2); t3 = fmaf(b3.z, we[6], t3);
    t0 = fmaf(b0.w, we[7], t0); t1 = fmaf(b1.w, we[7], t1); t2 = fmaf(b2.w, we[7], t2); t3 = fmaf(b3.w, we[7], t3);
    t0 = fmaxf(t0, 0.2f * t0) * attv;
    t1 = fmaxf(t1, 0.2f * t1) * attv;
    t2 = fmaxf(t2, 0.2f * t2) * attv;
    t3 = fmaxf(t3, 0.2f * t3) * attv;
    REDUCE32(t0); REDUCE32(t1); REDUCE32(t2); REDUCE32(t3);
    const float e0 = __expf(t0), e1 = __expf(t1), e2 = __expf(t2), e3 = __expf(t3);
    acc = fmaf(e0, x0, acc); den += e0;
    acc = fmaf(e1, x1, acc); den += e1;
    acc = fmaf(e2, x2, acc); den += e2;
    acc = fmaf(e3, x3, acc); den += e3;
  }
  for (; p < r1; ++p) {
    const int s = src_g[p];
    const float xv = xlb[(size_t)s * HD + lane];
    const float4 a = eg4[2 * p], b = eg4[2 * p + 1];
    float t = xv + xrv;
    t = fmaf(a.x, we[0], t); t = fmaf(a.y, we[1], t); t = fmaf(a.z, we[2], t); t = fmaf(a.w, we[3], t);
    t = fmaf(b.x, we[4], t); t = fmaf(b.y, we[5], t); t = fmaf(b.z, we[6], t); t = fmaf(b.w, we[7], t);
    t = fmaxf(t, 0.2f * t) * attv;
    REDUCE32(t);
    const float ex = __expf(t);
    acc = fmaf(ex, xv, acc);
    den += ex;
  }

  acc_b[((size_t)bk * NN + d) * HD + lane] = acc;
  if ((lane & 31) == 0) den_b[((size_t)bk * NN + d) * 2 + (lane >> 5)] = den;
}

// ---------------- fused combine(t) + node GEMV(t+1): 16 nodes per block ----------------
// T0=1: h-branch constant (h==0 => gh[k] = bl_h[k] + bias_h[k]) and c_old==0.
// h never leaves LDS: combine writes hs[][], GEMV consumes it for the h-branch xl/xr.

template <int T0>
__global__ __launch_bounds__(256, 4) void comb_node_k(
    const float* __restrict__ acc_b, const float* __restrict__ den_b,
    const float* __restrict__ bias_x, const float* __restrict__ bias_h,
    const float* __restrict__ ln_w, const float* __restrict__ ln_b,
    const float* __restrict__ x_next,
    const float* __restrict__ Wl_x, const float* __restrict__ bl_x,
    const float* __restrict__ Wr_x, const float* __restrict__ br_x,
    const float* __restrict__ Wl_h, const float* __restrict__ bl_h,
    const float* __restrict__ Wr_h, const float* __restrict__ br_h,
    float* __restrict__ xl, float* __restrict__ xr, float* __restrict__ c) {
  const int wv = threadIdx.x >> 6;
  const int lane = threadIdx.x & 63;
  const int n0 = blockIdx.x * 16;
  const int head = lane >> 5;
  __shared__ float hs[16][HD];
  __shared__ float xs[16][FI];

  for (int idx = threadIdx.x; idx < 16 * FI; idx += 256)
    xs[idx >> 5][idx & 31] = x_next[(size_t)n0 * FI + idx];

  // combine: wave wv handles nodes n0+wv+4i, i=0..3
#pragma unroll
  for (int i = 0; i < 4; ++i) {
    const int n = n0 + wv + 4 * i;
    float g4[4];
#pragma unroll
    for (int k = 0; k < 4; ++k) {
      float ax = acc_b[((size_t)k * NN + n) * HD + lane];
      float dx = den_b[((size_t)k * NN + n) * 2 + head];
      float gh;
      if (T0) {
        gh = bl_h[k * HD + lane] + bias_h[k * HD + lane];
      } else {
        float ah = acc_b[((size_t)(k + 4) * NN + n) * HD + lane];
        float dh = den_b[((size_t)(k + 4) * NN + n) * 2 + head];
        gh = ah / dh + bias_h[k * HD + lane];
      }
      g4[k] = ax / dx + bias_x[k * HD + lane] + gh;
    }
    float iv = 1.f / (1.f + __expf(-g4[0]));
    float fv = 1.f / (1.f + __expf(-g4[1]));
    float ov = 1.f / (1.f + __expf(-g4[2]));
    float gv = tanhf(g4[3]);
    float cn;
    if (T0) {
      cn = iv * gv;
    } else {
      cn = fmaf(fv, c[(size_t)n * HD + lane], iv * gv);
    }
    float nt = ov * tanhf(cn);
    float mu = nt;
#pragma unroll
    for (int o = 32; o >= 1; o >>= 1) mu += __shfl_xor(mu, o, 64);
    mu *= (1.f / 64.f);
    float df = nt - mu;
    float v2 = df * df;
#pragma unroll
    for (int o = 32; o >= 1; o >>= 1) v2 += __shfl_xor(v2, o, 64);
    v2 *= (1.f / 64.f);
    float hn = df * rsqrtf(v2 + 1e-5f) * ln_w[lane] + ln_b[lane];
    c[(size_t)n * HD + lane] = cn;
    hs[wv + 4 * i][lane] = hn;
  }
  __syncthreads();

  // GEMV for timestep t+1: wave wv = gate; x-branch (convs 0..3) then h-branch (convs 4..7)
  gemv16<FI>(xs, Wl_x + (size_t)wv * FI * HD, Wr_x + (size_t)wv * FI * HD,
             bl_x[wv * HD + lane], br_x[wv * HD + lane], lane, wv, n0, xl, xr);
  gemv16<HD>(hs, Wl_h + (size_t)wv * HD * HD, Wr_h + (size_t)wv * HD * HD,
             bl_h[wv * HD + lane], br_h[wv * HD + lane], lane, 4 + wv, n0, xl, xr);
}

// ---------------- final combine + fused output MLP; 4 nodes per block ----------------

__global__ __launch_bounds__(256, 8) void comb_out_k(
    const float* __restrict__ acc_b, const float* __restrict__ den_b,
    const float* __restrict__ bias_x, const float* __restrict__ bias_h,
    const float* __restrict__ ln_w, const float* __restrict__ ln_b,
    const float* __restrict__ w1, const float* __restrict__ b1,
    const float* __restrict__ w2, const float* __restrict__ b2,
    const float* __restrict__ c, float* __restrict__ out) {
  const int wv = threadIdx.x >> 6;
  const int lane = threadIdx.x & 63;
  const int n = blockIdx.x * 4 + wv;
  const int head = lane >> 5;
  float g4[4];
#pragma unroll
  for (int k = 0; k < 4; ++k) {
    float ax = acc_b[((size_t)k * NN + n) * HD + lane];
    float dx = den_b[((size_t)k * NN + n) * 2 + head];
    float ah = acc_b[((size_t)(k + 4) * NN + n) * HD + lane];
    float dh = den_b[((size_t)(k + 4) * NN + n) * 2 + head];
    g4[k] = ax / dx + bias_x[k * HD + lane] + ah / dh + bias_h[k * HD + lane];
  }
  float iv = 1.f / (1.f + __expf(-g4[0]));
  float fv = 1.f / (1.f + __expf(-g4[1]));
  float ov = 1.f / (1.f + __expf(-g4[2]));
  float gv = tanhf(g4[3]);
  float cn = fmaf(fv, c[(size_t)n * HD + lane], iv * gv);
  float nt = ov * tanhf(cn);
  float mu = nt;
#pragma unroll
  for (int o = 32; o >= 1; o >>= 1) mu += __shfl_xor(mu, o, 64);
  mu *= (1.f / 64.f);
  float df = nt - mu;
  float v2 = df * df;
#pragma unroll
  for (int o = 32; o >= 1; o >>= 1) v2 += __shfl_xor(v2, o, 64);
  v2 *= (1.f / 64.f);
  float hn = df * rsqrtf(v2 + 1e-5f) * ln_w[lane] + ln_b[lane];

  __shared__ float hsm[4][HD];
  __shared__ float zs[4][HD];
  hsm[wv][lane] = hn;
  __syncthreads();
  float a = b1[lane];
  for (int kk = 0; kk < HD; ++kk) a += hsm[wv][kk] * w1[kk * HD + lane];
  zs[wv][lane] = 0.5f * a * (1.f + erff(a * 0.70710678118654752f));  // exact (erf) GELU
  __syncthreads();
  if (lane < OD) {
    float o = b2[lane];
    for (int kk = 0; kk < HD; ++kk) o += zs[wv][kk] * w2[kk * OD + lane];
    out[(size_t)n * OD + lane] = o;
  }
}

// ---------------- host orchestration ----------------

extern "C" void kernel_launch(void* const* d_in, const int* in_sizes, int n_in,
                              void* d_out, int out_size, void* d_ws, size_t ws_size,
                              hipStream_t stream) {
  const float* x_seq   = (const float*)d_in[0];
  const float* edge_attr = (const float*)d_in[1];
  const int*   ei      = (const int*)d_in[2];
  const float* Wl_x    = (const float*)d_in[3];
  const float* bl_x    = (const float*)d_in[4];
  const float* Wr_x    = (const float*)d_in[5];
  const float* br_x    = (const float*)d_in[6];
  const float* We_x    = (const float*)d_in[7];
  const float* att_x   = (const float*)d_in[8];
  const float* bias_x  = (const float*)d_in[9];
  const float* Wl_h    = (const float*)d_in[10];
  const float* bl_h    = (const float*)d_in[11];
  const float* Wr_h    = (const float*)d_in[12];
  const float* br_h    = (const float*)d_in[13];
  const float* We_h    = (const float*)d_in[14];
  const float* att_h   = (const float*)d_in[15];
  const float* bias_h  = (const float*)d_in[16];
  const float* ln_w    = (const float*)d_in[17];
  const float* ln_b    = (const float*)d_in[18];
  const float* w1      = (const float*)d_in[19];
  const float* b1      = (const float*)d_in[20];
  const float* w2      = (const float*)d_in[21];
  const float* b2      = (const float*)d_in[22];
  float* out = (float*)d_out;

  char* p = (char*)d_ws;
  size_t off = 0;
  auto take = [&](size_t bytes) -> char* {
    char* r = p + off;
    off += (bytes + 255) & ~(size_t)255;
    return r;
  };
  // zero-span buffers first (only cnt, cursor need zeroing)
  int*   cnt      = (int*)take(NN * sizeof(int));
  int*   cursor   = (int*)take(NN * sizeof(int));
  size_t zero_bytes = off;                       // 256-aligned, float4-divisible
  float* cbuf     = (float*)take((size_t)NN * HD * sizeof(float));
  int*   rowptr2  = (int*)take((NN + 1) * sizeof(int));
  int*   src_g    = (int*)take((EE + NN) * sizeof(int));
  float* ea_g     = (float*)take((size_t)(EE + NN) * DE * sizeof(float));
  float* xl       = (float*)take((size_t)8 * NN * HD * sizeof(float));
  float* xr       = (float*)take((size_t)8 * NN * HD * sizeof(float));
  float* acc_b    = (float*)take((size_t)8 * NN * HD * sizeof(float));
  float* den_b    = (float*)take((size_t)8 * NN * 2 * sizeof(float));

  const int n4 = (int)(zero_bytes / 16);
  zero_k<<<40, 256, 0, stream>>>((float4*)d_ws, n4);
  hist_k<<<(EE + 255) / 256, 256, 0, stream>>>(ei, cnt);
  scan_k<<<1, 1024, 0, stream>>>(cnt, rowptr2);
  scatter_k<<<(EE + 255) / 256, 256, 0, stream>>>(ei, rowptr2, cursor, src_g, edge_attr, ea_g);
  selfmean_k<<<(NN + 3) / 4, 256, 0, stream>>>(rowptr2, src_g, ea_g);

  // t = 0: x-branch GEMV only (h == 0), 4-conv edge pass
  node0_k<<<NN / 16, 256, 0, stream>>>(x_seq, Wl_x, bl_x, Wr_x, br_x, xl, xr);
  edge_k<<<4 * NN / 4, 256, 0, stream>>>(rowptr2, src_g, ea_g, xl, xr,
                                         att_x, att_h, We_x, We_h, acc_b, den_b);
  // combine(t=0) + GEMV(t=1)
  comb_node_k<1><<<NN / 16, 256, 0, stream>>>(acc_b, den_b, bias_x, bias_h, ln_w, ln_b,
                                              x_seq + (size_t)1 * NN * FI,
                                              Wl_x, bl_x, Wr_x, br_x, Wl_h, bl_h, Wr_h, br_h,
                                              xl, xr, cbuf);
  edge_k<<<8 * NN / 4, 256, 0, stream>>>(rowptr2, src_g, ea_g, xl, xr,
                                         att_x, att_h, We_x, We_h, acc_b, den_b);
  // combine(t=1) + GEMV(t=2)
  comb_node_k<0><<<NN / 16, 256, 0, stream>>>(acc_b, den_b, bias_x, bias_h, ln_w, ln_b,
                                              x_seq + (size_t)2 * NN * FI,
                                              Wl_x, bl_x, Wr_x, br_x, Wl_h, bl_h, Wr_h, br_h,
                                              xl, xr, cbuf);
  edge_k<<<8 * NN / 4, 256, 0, stream>>>(rowptr2, src_g, ea_g, xl, xr,
                                         att_x, att_h, We_x, We_h, acc_b, den_b);
  // combine(t=2) + output MLP
  comb_out_k<<<NN / 4, 256, 0, stream>>>(acc_b, den_b, bias_x, bias_h, ln_w, ln_b,
                                         w1, b1, w2, b2, cbuf, out);
}

// Round 16
// 287.681 us; speedup vs baseline: 1.0478x; 1.0478x over previous
//
#include <hip/hip_runtime.h>
#include <math.h>

#define NN 10000
#define EE 160000
#define FI 32
#define DE 8
#define HD 64
#define TT 3
#define OD 12

// ---------------- bulk zero (cnt, cursor only) ----------------

__global__ __launch_bounds__(256) void zero_k(float4* __restrict__ base, int n4) {
  for (int i = blockIdx.x * 256 + threadIdx.x; i < n4; i += gridDim.x * 256)
    base[i] = float4{0.f, 0.f, 0.f, 0.f};
}

// ---------------- CSR construction (padded: +1 self-loop slot per row) ----------------

__global__ __launch_bounds__(256) void hist_k(const int* __restrict__ ei, int* __restrict__ cnt) {
  int e = blockIdx.x * 256 + threadIdx.x;
  if (e < EE) atomicAdd(&cnt[ei[EE + e]], 1);
}

// one-pass scan: rowptr2[i] = exclusive_scan(cnt)[i] + i  (+1 slot per row for the self loop)
__global__ __launch_bounds__(1024) void scan_k(const int* __restrict__ cnt, int* __restrict__ rowptr2) {
  __shared__ int wsum[16];
  const int tid = threadIdx.x, lane = tid & 63, wid = tid >> 6;
  const int i0 = tid * 10;
  int v[10];
  int tot = 0;
#pragma unroll
  for (int j = 0; j < 10; ++j) {
    int i = i0 + j;
    v[j] = (i < NN) ? cnt[i] : 0;
    tot += v[j];
  }
  int s = tot;
#pragma unroll
  for (int o = 1; o < 64; o <<= 1) {
    int t = __shfl_up(s, o, 64);
    if (lane >= o) s += t;
  }
  if (lane == 63) wsum[wid] = s;
  __syncthreads();
  if (wid == 0) {
    int ws = (lane < 16) ? wsum[lane] : 0;
#pragma unroll
    for (int o = 1; o < 16; o <<= 1) {
      int t = __shfl_up(ws, o, 64);
      if (lane >= o) ws += t;
    }
    if (lane < 16) wsum[lane] = ws;
  }
  __syncthreads();
  int base = s - tot + (wid > 0 ? wsum[wid - 1] : 0);
  int run = 0;
#pragma unroll
  for (int j = 0; j < 10; ++j) {
    int i = i0 + j;
    if (i < NN) rowptr2[i] = base + run + i;
    run += v[j];
  }
  if (tid == 1023) rowptr2[NN] = base + run + NN;
}

// scatter edges into CSR order; write ea_g in place (plain stores, no fp atomics)
__global__ __launch_bounds__(256) void scatter_k(const int* __restrict__ ei, const int* __restrict__ rowptr2,
                                                 int* __restrict__ cursor, int* __restrict__ src_g,
                                                 const float* __restrict__ ea, float* __restrict__ ea_g) {
  int e = blockIdx.x * 256 + threadIdx.x;
  if (e >= EE) return;
  int s = ei[e], d = ei[EE + e];
  int pos = rowptr2[d] + atomicAdd(&cursor[d], 1);
  src_g[pos] = s;
  const float4* s4 = reinterpret_cast<const float4*>(ea + (size_t)e * DE);
  float4* d4 = reinterpret_cast<float4*>(ea_g + (size_t)pos * DE);
  d4[0] = s4[0];
  d4[1] = s4[1];
}

// self-loop slot: mean of the row's edge attrs. One wave per node.
__global__ __launch_bounds__(256) void selfmean_k(const int* __restrict__ rowptr2, int* __restrict__ src_g,
                                                  float* __restrict__ ea_g) {
  int n = blockIdx.x * 4 + (threadIdx.x >> 6);
  int lane = threadIdx.x & 63;
  if (n >= NN) return;
  int r0 = rowptr2[n], r1 = rowptr2[n + 1];
  int deg = r1 - r0 - 1;
  int j = lane >> 3, dd = lane & 7;
  float s = 0.f;
  for (int base = 0; base < deg; base += 8) {
    int idx = base + j;
    if (idx < deg) s += ea_g[(size_t)(r0 + idx) * DE + dd];
  }
#pragma unroll
  for (int o = 8; o < 64; o <<= 1) s += __shfl_xor(s, o, 64);
  if (lane < 8) ea_g[(size_t)(r1 - 1) * DE + lane] = s / (float)(deg > 0 ? deg : 1);
  if (lane == 0) src_g[r1 - 1] = n;
}

// ---------------- node phase: xl/xr; 8 nodes per block; b128 LDS reads ----------------
// gridDim.y = 1 at t=0 (x-branch only; h==0 makes the h-branch constant), 2 otherwise.

__global__ __launch_bounds__(256) void node_k(const float* __restrict__ x_t, const float* __restrict__ h,
                                              const float* __restrict__ Wl_x, const float* __restrict__ bl_x,
                                              const float* __restrict__ Wr_x, const float* __restrict__ br_x,
                                              const float* __restrict__ Wl_h, const float* __restrict__ bl_h,
                                              const float* __restrict__ Wr_h, const float* __restrict__ br_h,
                                              float* __restrict__ xl, float* __restrict__ xr) {
  const int n0 = blockIdx.x * 8;
  const int b = blockIdx.y;
  const int k = threadIdx.x >> 6;
  const int lane = threadIdx.x & 63;
  const int K = b ? HD : FI;
  const int ksh = b ? 6 : 5;
  __shared__ float inp[8][HD];   // row-major: one row per node
  const float* srcbase = b ? (h + (size_t)n0 * HD) : (x_t + (size_t)n0 * FI);
  for (int idx = threadIdx.x; idx < 8 * K; idx += 256)
    inp[idx >> ksh][idx & (K - 1)] = srcbase[idx];
  __syncthreads();

  const float* Wl = (b ? Wl_h : Wl_x) + (size_t)k * K * HD;
  const float* Wr = (b ? Wr_h : Wr_x) + (size_t)k * K * HD;
  const float blv = (b ? bl_h : bl_x)[k * HD + lane];
  const float brv = (b ? br_h : br_x)[k * HD + lane];
  float al[8], ar[8];
#pragma unroll
  for (int j = 0; j < 8; ++j) { al[j] = blv; ar[j] = brv; }
  for (int kk = 0; kk < K; kk += 4) {
    float wl[4], wr[4];
#pragma unroll
    for (int q = 0; q < 4; ++q) {
      wl[q] = Wl[(kk + q) * HD + lane];
      wr[q] = Wr[(kk + q) * HD + lane];
    }
#pragma unroll
    for (int j = 0; j < 8; ++j) {
      const float4 v4 = *reinterpret_cast<const float4*>(&inp[j][kk]);  // LDS b128 broadcast
      al[j] = fmaf(v4.x, wl[0], al[j]); ar[j] = fmaf(v4.x, wr[0], ar[j]);
      al[j] = fmaf(v4.y, wl[1], al[j]); ar[j] = fmaf(v4.y, wr[1], ar[j]);
      al[j] = fmaf(v4.z, wl[2], al[j]); ar[j] = fmaf(v4.z, wr[2], ar[j]);
      al[j] = fmaf(v4.w, wl[3], al[j]); ar[j] = fmaf(v4.w, wr[3], ar[j]);
    }
  }
#pragma unroll
  for (int j = 0; j < 8; ++j) {
    size_t o = (((size_t)b * 4 + k) * NN + (n0 + j)) * HD + lane;
    xl[o] = al[j];
    xr[o] = ar[j];
  }
}

// ---------------- edge phase: one wave per (conv, node); round-7 inner loop (fastest) ----------------

template <int CTRL>
__device__ __forceinline__ float dpp_ror_add(float t) {
  int r = __builtin_amdgcn_update_dpp(0, __float_as_int(t), CTRL, 0xF, 0xF, true);
  return t + __int_as_float(r);
}
#define REDUCE32(t) do { \
  t = dpp_ror_add<0x128>(t); /* row_ror:8 */ \
  t = dpp_ror_add<0x124>(t); /* row_ror:4 */ \
  t = dpp_ror_add<0x122>(t); /* row_ror:2 */ \
  t = dpp_ror_add<0x121>(t); /* row_ror:1 */ \
  t += __int_as_float(__builtin_amdgcn_ds_swizzle(__float_as_int(t), 0x401F)); /* xor16 */ \
} while (0)

__global__ __launch_bounds__(256, 4) void edge_k(
    const int* __restrict__ rowptr2, const int* __restrict__ src_g, const float* __restrict__ ea_g,
    const float* __restrict__ xl, const float* __restrict__ xr,
    const float* __restrict__ att_x, const float* __restrict__ att_h,
    const float* __restrict__ We_x, const float* __restrict__ We_h,
    float* __restrict__ acc_b, float* __restrict__ den_b) {
  const int lane = threadIdx.x & 63;
  const int wid = threadIdx.x >> 6;
  // bijective XCD swizzle for arbitrary grid size (m204 form)
  const int nwg = gridDim.x;
  const int bid = blockIdx.x;
  const int q = nwg >> 3, r = nwg & 7;
  const int xcd = bid & 7;
  const int swz = (xcd < r ? xcd * (q + 1) : r * (q + 1) + (xcd - r) * q) + (bid >> 3);
  const int w = __builtin_amdgcn_readfirstlane(swz * 4 + wid);
  const int bk = w / NN;          // conv index (scalar); 0..3 at t=0, 0..7 otherwise
  const int d = w - bk * NN;      // dst node (scalar)
  const int k = bk & 3;
  const bool isx = (bk < 4);

  const float xrv = xr[((size_t)bk * NN + d) * HD + lane];
  const float attv = (isx ? att_x : att_h)[k * HD + lane];
  const float* Wep = (isx ? We_x : We_h) + (size_t)k * DE * HD;
  float we[DE];
#pragma unroll
  for (int dd = 0; dd < DE; ++dd) we[dd] = Wep[dd * HD + lane];
  const float* xlb = xl + (size_t)bk * NN * HD;
  const float4* eg4 = reinterpret_cast<const float4*>(ea_g);

  const int r0 = rowptr2[d];
  const int r1 = rowptr2[d + 1];
  float acc = 0.f, den = 0.f;

  int p = r0;
  for (; p + 4 <= r1; p += 4) {
    const int s0 = src_g[p + 0], s1 = src_g[p + 1], s2 = src_g[p + 2], s3 = src_g[p + 3];
    const float x0 = xlb[(size_t)s0 * HD + lane];
    const float x1 = xlb[(size_t)s1 * HD + lane];
    const float x2 = xlb[(size_t)s2 * HD + lane];
    const float x3 = xlb[(size_t)s3 * HD + lane];
    const float4 a0 = eg4[2 * (p + 0)], b0 = eg4[2 * (p + 0) + 1];
    const float4 a1 = eg4[2 * (p + 1)], b1 = eg4[2 * (p + 1) + 1];
    const float4 a2 = eg4[2 * (p + 2)], b2 = eg4[2 * (p + 2) + 1];
    const float4 a3 = eg4[2 * (p + 3)], b3 = eg4[2 * (p + 3) + 1];
    float t0 = x0 + xrv, t1 = x1 + xrv, t2 = x2 + xrv, t3 = x3 + xrv;
    t0 = fmaf(a0.x, we[0], t0); t1 = fmaf(a1.x, we[0], t1); t2 = fmaf(a2.x, we[0], t2); t3 = fmaf(a3.x, we[0], t3);
    t0 = fmaf(a0.y, we[1], t0); t1 = fmaf(a1.y, we[1], t1); t2 = fmaf(a2.y, we[1], t2); t3 = fmaf(a3.y, we[1], t3);
    t0 = fmaf(a0.z, we[2], t0); t1 = fmaf(a1.z, we[2], t1); t2 = fmaf(a2.z, we[2], t2); t3 = fmaf(a3.z, we[2], t3);
    t0 = fmaf(a0.w, we[3], t0); t1 = fmaf(a1.w, we[3], t1); t2 = fmaf(a2.w, we[3], t2); t3 = fmaf(a3.w, we[3], t3);
    t0 = fmaf(b0.x, we[4], t0); t1 = fmaf(b1.x, we[4], t1); t2 = fmaf(b2.x, we[4], t2); t3 = fmaf(b3.x, we[4], t3);
    t0 = fmaf(b0.y, we[5], t0); t1 = fmaf(b1.y, we[5], t1); t2 = fmaf(b2.y, we[5], t2); t3 = fmaf(b3.y, we[5], t3);
    t0 = fmaf(b0.z, we[6], t0); t1 = fmaf(b1.z, we[6], t1); t2 = fmaf(b2.z, we[6], t2); t3 = fmaf(b3.z, we[6], t3);
    t0 = fmaf(b0.w, we[7], t0); t1 = fmaf(b1.w, we[7], t1); t2 = fmaf(b2.w, we[7], t2); t3 = fmaf(b3.w, we[7], t3);
    t0 = fmaxf(t0, 0.2f * t0) * attv;
    t1 = fmaxf(t1, 0.2f * t1) * attv;
    t2 = fmaxf(t2, 0.2f * t2) * attv;
    t3 = fmaxf(t3, 0.2f * t3) * attv;
    REDUCE32(t0); REDUCE32(t1); REDUCE32(t2); REDUCE32(t3);
    const float e0 = __expf(t0), e1 = __expf(t1), e2 = __expf(t2), e3 = __expf(t3);
    acc = fmaf(e0, x0, acc); den += e0;
    acc = fmaf(e1, x1, acc); den += e1;
    acc = fmaf(e2, x2, acc); den += e2;
    acc = fmaf(e3, x3, acc); den += e3;
  }
  for (; p < r1; ++p) {
    const int s = src_g[p];
    const float xv = xlb[(size_t)s * HD + lane];
    const float4 a = eg4[2 * p], b = eg4[2 * p + 1];
    float t = xv + xrv;
    t = fmaf(a.x, we[0], t); t = fmaf(a.y, we[1], t); t = fmaf(a.z, we[2], t); t = fmaf(a.w, we[3], t);
    t = fmaf(b.x, we[4], t); t = fmaf(b.y, we[5], t); t = fmaf(b.z, we[6], t); t = fmaf(b.w, we[7], t);
    t = fmaxf(t, 0.2f * t) * attv;
    REDUCE32(t);
    const float ex = __expf(t);
    acc = fmaf(ex, xv, acc);
    den += ex;
  }

  acc_b[((size_t)bk * NN + d) * HD + lane] = acc;
  if ((lane & 31) == 0) den_b[((size_t)bk * NN + d) * 2 + (lane >> 5)] = den;
}

// ---------------- combine: LSTM gates + LayerNorm (+ fused output MLP at final step) ----------------
// T0=1: h-branch constant (h==0 => gh[k] = bl_h[k] + bias_h[k]) and c_old==0.
// OUTF=1: final step — compute gelu-MLP output in-block, skip h/c stores.

template <int T0, int OUTF>
__global__ __launch_bounds__(256, 8) void combine_k(
    const float* __restrict__ acc_b, const float* __restrict__ den_b,
    const float* __restrict__ bias_x, const float* __restrict__ bias_h,
    const float* __restrict__ bl_h,
    const float* __restrict__ ln_w, const float* __restrict__ ln_b,
    const float* __restrict__ w1, const float* __restrict__ b1,
    const float* __restrict__ w2, const float* __restrict__ b2,
    float* __restrict__ h, float* __restrict__ c, float* __restrict__ out) {
  const int wv = threadIdx.x >> 6;
  const int lane = threadIdx.x & 63;
  const int n = blockIdx.x * 4 + wv;        // NN % 4 == 0: always valid
  const int head = lane >> 5;
  float g4[4];
#pragma unroll
  for (int k = 0; k < 4; ++k) {
    float ax = acc_b[((size_t)k * NN + n) * HD + lane];
    float dx = den_b[((size_t)k * NN + n) * 2 + head];
    float gh;
    if (T0) {
      gh = bl_h[k * HD + lane] + bias_h[k * HD + lane];
    } else {
      float ah = acc_b[((size_t)(k + 4) * NN + n) * HD + lane];
      float dh = den_b[((size_t)(k + 4) * NN + n) * 2 + head];
      gh = ah / dh + bias_h[k * HD + lane];
    }
    g4[k] = ax / dx + bias_x[k * HD + lane] + gh;
  }
  float iv = 1.f / (1.f + __expf(-g4[0]));
  float fv = 1.f / (1.f + __expf(-g4[1]));
  float ov = 1.f / (1.f + __expf(-g4[2]));
  float gv = tanhf(g4[3]);
  float cn;
  if (T0) {
    cn = iv * gv;
  } else {
    float cold = c[(size_t)n * HD + lane];
    cn = fv * cold + iv * gv;
  }
  float nt = ov * tanhf(cn);
  float mu = nt;
#pragma unroll
  for (int o = 32; o >= 1; o >>= 1) mu += __shfl_xor(mu, o, 64);
  mu *= (1.f / 64.f);
  float df = nt - mu;
  float v2 = df * df;
#pragma unroll
  for (int o = 32; o >= 1; o >>= 1) v2 += __shfl_xor(v2, o, 64);
  v2 *= (1.f / 64.f);
  float hn = df * rsqrtf(v2 + 1e-5f) * ln_w[lane] + ln_b[lane];

  if (OUTF) {
    __shared__ float hsm[4][HD];
    __shared__ float zs[4][HD];
    hsm[wv][lane] = hn;
    __syncthreads();
    float a = b1[lane];
    for (int kk = 0; kk < HD; ++kk) a += hsm[wv][kk] * w1[kk * HD + lane];
    zs[wv][lane] = 0.5f * a * (1.f + erff(a * 0.70710678118654752f));  // exact (erf) GELU
    __syncthreads();
    if (lane < OD) {
      float o = b2[lane];
      for (int kk = 0; kk < HD; ++kk) o += zs[wv][kk] * w2[kk * OD + lane];
      out[(size_t)n * OD + lane] = o;
    }
  } else {
    c[(size_t)n * HD + lane] = cn;
    h[(size_t)n * HD + lane] = hn;
  }
}

// ---------------- host orchestration ----------------

extern "C" void kernel_launch(void* const* d_in, const int* in_sizes, int n_in,
                              void* d_out, int out_size, void* d_ws, size_t ws_size,
                              hipStream_t stream) {
  const float* x_seq   = (const float*)d_in[0];
  const float* edge_attr = (const float*)d_in[1];
  const int*   ei      = (const int*)d_in[2];
  const float* Wl_x    = (const float*)d_in[3];
  const float* bl_x    = (const float*)d_in[4];
  const float* Wr_x    = (const float*)d_in[5];
  const float* br_x    = (const float*)d_in[6];
  const float* We_x    = (const float*)d_in[7];
  const float* att_x   = (const float*)d_in[8];
  const float* bias_x  = (const float*)d_in[9];
  const float* Wl_h    = (const float*)d_in[10];
  const float* bl_h    = (const float*)d_in[11];
  const float* Wr_h    = (const float*)d_in[12];
  const float* br_h    = (const float*)d_in[13];
  const float* We_h    = (const float*)d_in[14];
  const float* att_h   = (const float*)d_in[15];
  const float* bias_h  = (const float*)d_in[16];
  const float* ln_w    = (const float*)d_in[17];
  const float* ln_b    = (const float*)d_in[18];
  const float* w1      = (const float*)d_in[19];
  const float* b1      = (const float*)d_in[20];
  const float* w2      = (const float*)d_in[21];
  const float* b2      = (const float*)d_in[22];
  float* out = (float*)d_out;

  char* p = (char*)d_ws;
  size_t off = 0;
  auto take = [&](size_t bytes) -> char* {
    char* r = p + off;
    off += (bytes + 255) & ~(size_t)255;
    return r;
  };
  // zero-span buffers first (only cnt, cursor need zeroing)
  int*   cnt      = (int*)take(NN * sizeof(int));
  int*   cursor   = (int*)take(NN * sizeof(int));
  size_t zero_bytes = off;                       // 256-aligned, float4-divisible
  float* hbuf     = (float*)take((size_t)NN * HD * sizeof(float));
  float* cbuf     = (float*)take((size_t)NN * HD * sizeof(float));
  int*   rowptr2  = (int*)take((NN + 1) * sizeof(int));
  int*   src_g    = (int*)take((EE + NN) * sizeof(int));
  float* ea_g     = (float*)take((size_t)(EE + NN) * DE * sizeof(float));
  float* xl       = (float*)take((size_t)8 * NN * HD * sizeof(float));
  float* xr       = (float*)take((size_t)8 * NN * HD * sizeof(float));
  float* acc_b    = (float*)take((size_t)8 * NN * HD * sizeof(float));
  float* den_b    = (float*)take((size_t)8 * NN * 2 * sizeof(float));

  const int n4 = (int)(zero_bytes / 16);
  zero_k<<<40, 256, 0, stream>>>((float4*)d_ws, n4);
  hist_k<<<(EE + 255) / 256, 256, 0, stream>>>(ei, cnt);
  scan_k<<<1, 1024, 0, stream>>>(cnt, rowptr2);
  scatter_k<<<(EE + 255) / 256, 256, 0, stream>>>(ei, rowptr2, cursor, src_g, edge_attr, ea_g);
  selfmean_k<<<(NN + 3) / 4, 256, 0, stream>>>(rowptr2, src_g, ea_g);

  for (int t = 0; t < TT; ++t) {
    const float* x_t = x_seq + (size_t)t * NN * FI;
    const int nconv = (t == 0) ? 4 : 8;   // h==0 at t=0: h-branch GAT is constant
    node_k<<<dim3(NN / 8, t == 0 ? 1 : 2), 256, 0, stream>>>(
        x_t, hbuf, Wl_x, bl_x, Wr_x, br_x, Wl_h, bl_h, Wr_h, br_h, xl, xr);
    edge_k<<<nconv * NN / 4, 256, 0, stream>>>(rowptr2, src_g, ea_g, xl, xr,
                                               att_x, att_h, We_x, We_h, acc_b, den_b);
    if (t == 0)
      combine_k<1, 0><<<NN / 4, 256, 0, stream>>>(acc_b, den_b, bias_x, bias_h, bl_h,
                                                  ln_w, ln_b, w1, b1, w2, b2, hbuf, cbuf, out);
    else if (t == 1)
      combine_k<0, 0><<<NN / 4, 256, 0, stream>>>(acc_b, den_b, bias_x, bias_h, bl_h,
                                                  ln_w, ln_b, w1, b1, w2, b2, hbuf, cbuf, out);
    else
      combine_k<0, 1><<<NN / 4, 256, 0, stream>>>(acc_b, den_b, bias_x, bias_h, bl_h,
                                                  ln_w, ln_b, w1, b1, w2, b2, hbuf, cbuf, out);
  }
}